// Round 6
// baseline (82.345 us; speedup 1.0000x reference)
//
#include <hip/hip_runtime.h>

// Problem constants
#define B_    8
#define CIN_  16
#define COUT_ 16
#define KS_   13
#define AS_   12
#define P_    4096
#define R_    12
#define M_    192          // COUT_ * R_
#define KTOT  2496         // CIN_ * KS_ * AS_   (reduction dim)
#define BN    128          // p-tile per workgroup (256 WGs, 1/CU)
#define KT    96           // K-tile (8 (c,k) pairs x 12 a)
#define NSTEP 26           // KTOT / KT
#define LDP   104          // LDS pitch (96 + 8 pad; 2-way b128 conflict = free)

typedef float  f32x4  __attribute__((ext_vector_type(4)));
typedef __bf16 bf16x4 __attribute__((ext_vector_type(4)));
typedef __bf16 bf16x8 __attribute__((ext_vector_type(8)));

// ---------------------------------------------------------------------------
// Kernel 1: expand W into MFMA-FRAGMENT-ORDERED WmatF.
// Fragment (kt, mt, ks): 64 lanes x 16B, lane l holds
//   Wrow = mt*16 + (l&15),  kappa = kt*96 + ks*32 + (l>>4)*8 + e, e=0..7
// where Wrow=(d*12+r), kappa=(c*13+k)*12+a,
//   Wfull[d,c,r,k,a] = W[d,c, idx_map[ tivr[r,k]*12 + tir[r,a] ]].
// Flat: WmatF[(((kt*12+mt)*3+ks)*64 + l)*8 + e]   (958 KB)
// ---------------------------------------------------------------------------
__global__ void build_wmatf(const float* __restrict__ W,
                            const int* __restrict__ idx_map,
                            const int* __restrict__ tivr,   // [12][13]
                            const int* __restrict__ tir,    // [12][12]
                            __bf16* __restrict__ WmatF) {
  int gid  = blockIdx.x * blockDim.x + threadIdx.x;   // 0..59903
  int lane = gid & 63;
  int fid  = gid >> 6;          // 0..935
  int kt   = fid / 36;
  int rem  = fid - kt * 36;
  int mt   = rem / 3;
  int ks   = rem - mt * 3;

  int row = mt * 16 + (lane & 15);
  int d = row / R_;
  int r = row - d * R_;

  bf16x8 v;
#pragma unroll
  for (int e = 0; e < 8; ++e) {
    int kap = kt * KT + ks * 32 + (lane >> 4) * 8 + e;
    int c = kap / (KS_ * AS_);
    int t = kap - c * (KS_ * AS_);
    int k = t / AS_;
    int a = t - k * AS_;
    int s = idx_map[tivr[r * KS_ + k] * AS_ + tir[r * AS_ + a]];
    v[e] = (__bf16)W[(d * CIN_ + c) * 36 + s];
  }
  *(bf16x8*)(WmatF + (size_t)gid * 8) = v;
}

// ---------------------------------------------------------------------------
// Kernel 2: out(b,d,p,r) = W(192 x 2496) @ X(2496 x [b,p])
// 256 WGs x 512 threads, BM=192 (x read exactly once from HBM).
// A-operand comes STRAIGHT FROM L2 (fragment-ordered WmatF, coalesced
// dwordx4 per lane) -- no W in LDS. Only X is staged in LDS (double-buffered,
// 53 KB). All loads unconditional; one lgkmcnt(0)+s_barrier per step; no
// vmcnt(0) drain anywhere.
// ---------------------------------------------------------------------------
__global__ __launch_bounds__(512, 2)
void s2conv(const float* __restrict__ x,
            const __bf16* __restrict__ WmatF,
            float* __restrict__ out) {
  __shared__ __bf16 Xs[2][BN][LDP];   // 2 x 26.6 KB

  const int tid  = threadIdx.x;
  const int lane = tid & 63;
  const int wave = tid >> 6;        // 0..7
  const int wm   = wave >> 2;       // 0..1  (96 m-rows each)
  const int wn   = wave & 3;        // 0..3  (32 p-cols each)
  const int l15  = lane & 15;
  const int l4   = lane >> 4;

  const int wg = blockIdx.x;        // 0..255
  const int b  = wg >> 5;           // 0..7
  const int p0 = (wg & 31) << 7;    // p tile base

  f32x4 acc[6][2];
#pragma unroll
  for (int i = 0; i < 6; ++i)
#pragma unroll
    for (int j = 0; j < 2; ++j)
      acc[i][j] = f32x4{0.f, 0.f, 0.f, 0.f};

  // ---- staging helpers (ALL loads unconditional) ---------------------------
  auto load_x = [&](int kt, f32x4 (&st)[6]) {
    int ck = kt * 8 + wave;   // wave's (c,k) pair: contiguous 6 KB span
    const f32x4* bp =
        (const f32x4*)(x + (size_t)(b * 208 + ck) * 49152 + (size_t)p0 * 12);
#pragma unroll
    for (int it = 0; it < 6; ++it) st[it] = bp[it * 64 + lane];
  };

  // A-fragments for this wave's 96 m-rows, direct from L2 (frag-ordered).
  auto load_a = [&](int kt, bf16x8 (&af)[18]) {
    const char* base = (const char*)WmatF +
        (size_t)(kt * 36 + wm * 18) * 1024 + lane * 16;
#pragma unroll
    for (int f = 0; f < 18; ++f)        // f = mt*3 + ks
      af[f] = *(const bf16x8*)(base + f * 1024);
  };

  auto write_X = [&](int buf, f32x4 (&st)[6]) {
    char* xsb = (char*)&Xs[buf][0][0];
#pragma unroll
    for (int it = 0; it < 6; ++it) {
      int f4i = it * 64 + lane;          // float4 index in this (c,k) span
      int pl  = f4i / 3;                 // p_local
      int a   = (f4i - pl * 3) * 4;      // a in {0,4,8}
      bf16x4 v = __builtin_convertvector(st[it], bf16x4);
      *(bf16x4*)(xsb + pl * (LDP * 2) + (wave * 12 + a) * 2) = v;
    }
  };

  auto mfma_step = [&](int buf, bf16x8 (&af)[18]) {
    const __bf16* xsb = &Xs[buf][0][0];
#pragma unroll
    for (int ks = 0; ks < 3; ++ks) {     // 3 x K=32
      const int col = ks * 32 + l4 * 8;
      bf16x8 bfr[2];
#pragma unroll
      for (int nt = 0; nt < 2; ++nt)
        bfr[nt] = *(const bf16x8*)(xsb + (wn * 32 + nt * 16 + l15) * LDP + col);
#pragma unroll
      for (int mt = 0; mt < 6; ++mt)
#pragma unroll
        for (int nt = 0; nt < 2; ++nt)
          acc[mt][nt] = __builtin_amdgcn_mfma_f32_16x16x32_bf16(
              af[mt * 3 + ks], bfr[nt], acc[mt][nt], 0, 0, 0);
    }
  };

  auto barrier = [&]() {
    asm volatile("s_waitcnt lgkmcnt(0)" ::: "memory");  // X writes visible
    __builtin_amdgcn_s_barrier();                        // NO vmcnt drain
  };

  // ---- prologue ------------------------------------------------------------
  f32x4  stA[6], stB[6];
  bf16x8 af[18];
  load_x(0, stA);
  load_x(1, stB);
  write_X(0, stA);
  barrier();

  // ---- main loop: 12 iterations, NO conditional loads ----------------------
  for (int kt = 0; kt < NSTEP - 2; kt += 2) {
    load_a(kt, af);                     // this tile's A-frags (L2, counted)
    load_x(kt + 2, stA);                // tile kt+2 -> set A
    __builtin_amdgcn_sched_barrier(0);
    write_X(1, stB);                    // tile kt+1 -> buf 1
    mfma_step(0, af);                   // tile kt   (buf 0)
    barrier();

    load_a(kt + 1, af);
    load_x(kt + 3, stB);                // tile kt+3 -> set B
    __builtin_amdgcn_sched_barrier(0);
    write_X(0, stA);                    // tile kt+2 -> buf 0
    mfma_step(1, af);                   // tile kt+1 (buf 1)
    barrier();
  }

  // ---- peeled tail: tiles 24 (buf 0) and 25 (buf 1), no x/X loads ----------
  load_a(24, af);
  write_X(1, stB);                      // tile 25 -> buf 1
  mfma_step(0, af);                     // tile 24
  barrier();
  load_a(25, af);
  mfma_step(1, af);                     // tile 25

  // ---- epilogue: store. m = d*12+r, lane's 4 regs = 4 consecutive r --------
#pragma unroll
  for (int mt = 0; mt < 6; ++mt) {
    int mrow0 = wm * 96 + mt * 16 + l4 * 4;   // r0 in {0,4,8} -> same d
    int d  = mrow0 / 12;
    int r0 = mrow0 - d * 12;
#pragma unroll
    for (int nt = 0; nt < 2; ++nt) {
      int p = p0 + wn * 32 + nt * 16 + l15;
      float* dst = out + (size_t)((b * 16 + d) * 4096 + p) * 12 + r0;
      *(f32x4*)dst = acc[mt][nt];   // 16B aligned: r0 in {0,4,8}
    }
  }
}

// ---------------------------------------------------------------------------
extern "C" void kernel_launch(void* const* d_in, const int* in_sizes, int n_in,
                              void* d_out, int out_size, void* d_ws, size_t ws_size,
                              hipStream_t stream) {
  const float* x       = (const float*)d_in[0];  // (8,16,13,4096,12) f32
  const float* W       = (const float*)d_in[1];  // (16,16,36) f32
  const int*   idx_map = (const int*)d_in[2];    // (156,)
  const int*   tivr    = (const int*)d_in[3];    // (12,13)
  const int*   tir     = (const int*)d_in[4];    // (12,12)
  float*       out     = (float*)d_out;          // (8,16,4096,12) f32
  __bf16*      WmatF   = (__bf16*)d_ws;          // 958 KB, fragment-ordered

  build_wmatf<<<dim3(117), dim3(512), 0, stream>>>(W, idx_map, tivr, tir, WmatF);
  s2conv<<<dim3(256), dim3(512), 0, stream>>>(x, WmatF, out);
}